// Round 6
// baseline (1811.993 us; speedup 1.0000x reference)
//
#include <hip/hip_runtime.h>
#include <math.h>

// F=4, T=12, C=512, HID=256, OUT=12
#define NF 48
#define TT 12

typedef __bf16 v8bf __attribute__((ext_vector_type(8)));
typedef float v4f __attribute__((ext_vector_type(4)));

// ---------------- small prep kernels ----------------

__global__ void k_init_deg(float* __restrict__ deg, int n) {
  int i = blockIdx.x * blockDim.x + threadIdx.x;
  if (i < n) deg[i] = 1.0f;
}

__global__ void k_scatter_deg(const int* __restrict__ dst, const float* __restrict__ w,
                              float* __restrict__ deg, int e) {
  int i = blockIdx.x * blockDim.x + threadIdx.x;
  if (i < e) atomicAdd(&deg[dst[i]], w[i]);
}

__global__ void k_dinv(const float* __restrict__ deg, float* __restrict__ dinv, int n) {
  int i = blockIdx.x * blockDim.x + threadIdx.x;
  if (i < n) dinv[i] = rsqrtf(fmaxf(deg[i], 1e-12f));
}

__global__ void k_zeroi(int* __restrict__ p, int n) {
  int i = blockIdx.x * blockDim.x + threadIdx.x;
  if (i < n) p[i] = 0;
}

// ---------------- CSR build (by dst) ----------------

__global__ void k_count(const int* __restrict__ dst, int* __restrict__ cnt, int e) {
  int i = blockIdx.x * blockDim.x + threadIdx.x;
  if (i < e) atomicAdd(&cnt[dst[i]], 1);
}

__global__ void k_scan(const int* __restrict__ cnt, int* __restrict__ offs, int n) {
  __shared__ int s[1024];
  __shared__ int carry;
  int tid = threadIdx.x;
  if (tid == 0) carry = 0;
  __syncthreads();
  for (int base = 0; base < n; base += 1024) {
    int v = (base + tid < n) ? cnt[base + tid] : 0;
    s[tid] = v;
    __syncthreads();
    for (int off = 1; off < 1024; off <<= 1) {
      int t = 0;
      if (tid >= off) t = s[tid - off];
      __syncthreads();
      s[tid] += t;
      __syncthreads();
    }
    if (base + tid < n) offs[base + tid] = carry + s[tid] - v;
    __syncthreads();
    if (tid == 0) carry += s[1023];
    __syncthreads();
  }
  if (tid == 0) offs[n] = carry;
}

__global__ void k_place(const int* __restrict__ src, const int* __restrict__ dst,
                        const float* __restrict__ w, const int* __restrict__ offs,
                        int* __restrict__ fill, int* __restrict__ csrc,
                        float* __restrict__ cw, int e) {
  int i = blockIdx.x * blockDim.x + threadIdx.x;
  if (i >= e) return;
  int d = dst[i];
  int p = offs[d] + atomicAdd(&fill[d], 1);
  csrc[p] = src[i];
  cw[p] = w[i];
}

__global__ void k_gather(const int* __restrict__ offs, const int* __restrict__ csrc,
                         const float* __restrict__ cw, const float* __restrict__ dinv,
                         const float* __restrict__ x, float* __restrict__ Y, int n) {
  int tg = blockIdx.x * blockDim.x + threadIdx.x;
  if (tg >= n * 12) return;
  int i = tg / 12, q = tg % 12;
  float di = dinv[i];
  const float4* x4 = (const float4*)x;
  float4 sv = x4[(size_t)i * 12 + q];
  float ax = di * sv.x, ay = di * sv.y, az = di * sv.z, aw = di * sv.w;
  int e1 = offs[i + 1];
  for (int e = offs[i]; e < e1; e++) {
    int s = csrc[e];
    float wv = cw[e] * dinv[s];
    float4 xv = x4[(size_t)s * 12 + q];
    ax = fmaf(wv, xv.x, ax); ay = fmaf(wv, xv.y, ay);
    az = fmaf(wv, xv.z, az); aw = fmaf(wv, xv.w, aw);
  }
  float4 o = make_float4(di * ax, di * ay, di * az, di * aw);
  ((float4*)Y)[(size_t)i * 12 + q] = o;
}

// ---------------- weight prep: pack into 64-k fragment tiles ----------------
// [n/TN][k/64][n%TN][k%64]
__device__ __forceinline__ size_t packIdx(int n, int k, int TN) {
  return (size_t)(n / TN) * TN * 512 + (size_t)(k >> 6) * TN * 64 +
         (size_t)(n % TN) * 64 + (k & 63);
}

// [z|r] bottom halves of Wz_l / Wr_l, TN=256
__global__ void k_t_zr(const float* __restrict__ Wzl, const float* __restrict__ Wrl,
                       __bf16* __restrict__ WT) {
  int idx = blockIdx.x * blockDim.x + threadIdx.x;
  if (idx >= 1024 * 512) return;
  int n = idx >> 9, k = idx & 511;
  float v = (n < 512) ? Wzl[(512 + k) * 512 + n] : Wrl[(512 + k) * 512 + (n - 512)];
  WT[packIdx(n, k, 256)] = (__bf16)v;
}

// Wh_l bottom half, TN=128
__global__ void k_t_h(const float* __restrict__ Whl, __bf16* __restrict__ WT) {
  int idx = blockIdx.x * blockDim.x + threadIdx.x;
  if (idx >= 512 * 512) return;
  int n = idx >> 9, k = idx & 511;
  WT[packIdx(n, k, 128)] = (__bf16)Whl[(512 + k) * 512 + n];
}

// W1, TN=256
__global__ void k_t_1(const float* __restrict__ W1, __bf16* __restrict__ WT) {
  int idx = blockIdx.x * blockDim.x + threadIdx.x;
  if (idx >= 256 * 512) return;
  int n = idx >> 9, k = idx & 511;
  WT[packIdx(n, k, 256)] = (__bf16)W1[k * 256 + n];
}

__global__ void k_build_eff(const float* __restrict__ Wg, const float* __restrict__ Wl,
                            const float* __restrict__ bg, const float* __restrict__ bl,
                            float* __restrict__ Weff, float* __restrict__ beff,
                            int ostride, int ooff) {
  int idx = blockIdx.x * blockDim.x + threadIdx.x;
  if (idx >= 5 * 512) return;
  int r = idx / 512, c = idx % 512;
  float s = 0.f;
  if (r < 4) {
    for (int k = 0; k < 512; k++) s += Wg[r * 512 + k] * Wl[k * 512 + c];
    Weff[r * ostride + ooff + c] = s;
  } else {
    for (int k = 0; k < 512; k++) s += bg[k] * Wl[k * 512 + c];
    beff[ooff + c] = s + bl[c];
  }
}

__global__ void k_softmax_att(const float* __restrict__ att, float* __restrict__ probs) {
  if (blockIdx.x == 0 && threadIdx.x == 0) {
    float m = -1e30f;
    for (int t = 0; t < TT; t++) m = fmaxf(m, att[t]);
    float e[TT], s = 0.f;
    for (int t = 0; t < TT; t++) { e[t] = expf(att[t] - m); s += e[t]; }
    for (int t = 0; t < TT; t++) probs[t] = e[t] / s;
  }
}

// ---------------- MFMA GEMM: A-panel in registers, B-only LDS ----------------
// Block = 4 waves, 64 rows (16 rows/wave), TN cols. A[16x512] preloaded to 64 VGPRs
// before the K-loop (MODE1 fuses *r). K-loop: 8 dbuf iterations of BK=64; only
// vmem is B (L2-hot, packed fragment tiles); XOR-swizzled LDS (2-way max).
// MODE 0: TN=256. epi: sigmoid(pre+Y@Weff+beff) -> z(cols<512)/r(cols>=512) bf16
// MODE 1: TN=128. A=(H*r). epi: ht=tanh(..); hn=z*hold+(1-z)*ht -> hist bf16
// MODE 2: TN=256. A=accRelu. epi: relu(pre+b1) -> T1 fp32
template <int MODE>
__global__ __launch_bounds__(256, 2) void k_mm(
    const __bf16* __restrict__ Abf, const __bf16* __restrict__ Bp,
    const __bf16* __restrict__ Rbf, const __bf16* __restrict__ Zbf,
    const float* __restrict__ Y, const float* __restrict__ Weff,
    const float* __restrict__ beff,
    float* __restrict__ Ofp, __bf16* __restrict__ Obf, __bf16* __restrict__ Obf2,
    int M, int t) {
  constexpr int TN = (MODE == 1) ? 128 : 256;
  constexpr int NT = TN / 16;   // 16 or 8 n-tiles per wave
  constexpr int CH = TN / 32;   // uint4 chunks per thread per 64k-dtile (8 or 4)
  constexpr int NoutW = (MODE == 0) ? 1024 : 512;
  __shared__ __bf16 sB[2][TN * 64];
  const int tid = threadIdx.x;
  const int row0 = blockIdx.y * 64;
  const int col0 = blockIdx.x * TN;
  const int w = tid >> 6, lane = tid & 63, lm = lane & 15, quad = lane >> 4;
  const int rw = row0 + w * 16 + lm;  // this lane's A row
  const bool aval = rw < M;

  v8bf zero8;
#pragma unroll
  for (int j = 0; j < 8; j++) zero8[j] = (__bf16)0.f;

  // ---- A panel preload: 16 k-tiles of 32 in regs (64 VGPR)
  v8bf ap[16];
  {
    const __bf16* Arow = Abf + (size_t)rw * 512 + quad * 8;
    const __bf16* Rrow = Rbf + (size_t)rw * 512 + quad * 8;
#pragma unroll
    for (int kt = 0; kt < 16; kt++) {
      if (aval) {
        v8bf h = *(const v8bf*)(Arow + kt * 32);
        if constexpr (MODE == 1) {
          v8bf r = *(const v8bf*)(Rrow + kt * 32);
#pragma unroll
          for (int j = 0; j < 8; j++) h[j] = (__bf16)((float)h[j] * (float)r[j]);
        }
        ap[kt] = h;
      } else {
        ap[kt] = zero8;
      }
    }
  }

  // ---- B staging (packed global -> swizzled LDS)
  const __bf16* Bbase = Bp + (size_t)col0 * 512;
  uint4 rb[CH];
  auto gloadB = [&](int kt2) {
    const __bf16* tb = Bbase + (size_t)kt2 * TN * 64;
#pragma unroll
    for (int c = 0; c < CH; c++)
      rb[c] = *(const uint4*)(tb + (size_t)(c * 256 + tid) * 8);
  };
  auto lstoreB = [&](int buf) {
#pragma unroll
    for (int c = 0; c < CH; c++) {
      int ch = c * 256 + tid;
      int col = ch >> 3, kc = ch & 7;
      *(uint4*)(&sB[buf][col * 64 + ((kc ^ (col & 7)) * 8)]) = rb[c];
    }
  };

  v4f acc4[NT];
#pragma unroll
  for (int i = 0; i < NT; i++) acc4[i] = (v4f){0.f, 0.f, 0.f, 0.f};

  gloadB(0);
  lstoreB(0);
  gloadB(1);
  __syncthreads();

#pragma unroll
  for (int i = 0; i < 8; i++) {
    if (i < 7) {
      lstoreB((i + 1) & 1);        // rb holds dtile i+1
      if (i < 6) gloadB(i + 2);    // issue early; lands before next barrier
    }
#pragma unroll
    for (int ks = 0; ks < 2; ks++) {
      const v8bf a = ap[2 * i + ks];
#pragma unroll
      for (int ni = 0; ni < NT; ni++) {
        int col = ni * 16 + lm;
        v8bf bfr = *(const v8bf*)(
            &sB[i & 1][col * 64 + (((ks * 4 + quad) ^ (col & 7)) * 8)]);
        acc4[ni] = __builtin_amdgcn_mfma_f32_16x16x32_bf16(a, bfr, acc4[ni], 0, 0, 0);
      }
    }
    __syncthreads();
  }

  // ---- epilogue: C row = row0 + w*16 + quad*4 + r, col = col0 + ni*16 + lm
  if constexpr (MODE == 0) {
    __bf16* dst = (col0 < 512) ? Obf : Obf2;
    const int cof = (col0 < 512) ? col0 : col0 - 512;
#pragma unroll
    for (int r = 0; r < 4; r++) {
      int rg = row0 + w * 16 + quad * 4 + r;
      if (rg >= M) continue;
      const float* yr = Y + (size_t)rg * NF;
      float yv0 = yr[0 * TT + t], yv1 = yr[1 * TT + t];
      float yv2 = yr[2 * TT + t], yv3 = yr[3 * TT + t];
#pragma unroll
      for (int ni = 0; ni < NT; ni++) {
        int cg = col0 + ni * 16 + lm;
        float pre = acc4[ni][r] + beff[cg] + yv0 * Weff[cg] +
                    yv1 * Weff[NoutW + cg] + yv2 * Weff[2 * NoutW + cg] +
                    yv3 * Weff[3 * NoutW + cg];
        float s = 1.f / (1.f + expf(-pre));
        dst[(size_t)rg * 512 + (cof + ni * 16 + lm)] = (__bf16)s;
      }
    }
  } else if constexpr (MODE == 1) {
#pragma unroll
    for (int r = 0; r < 4; r++) {
      int rg = row0 + w * 16 + quad * 4 + r;
      if (rg >= M) continue;
      const float* yr = Y + (size_t)rg * NF;
      float yv0 = yr[0 * TT + t], yv1 = yr[1 * TT + t];
      float yv2 = yr[2 * TT + t], yv3 = yr[3 * TT + t];
#pragma unroll
      for (int ni = 0; ni < NT; ni++) {
        int cg = col0 + ni * 16 + lm;
        float pre = acc4[ni][r] + beff[cg] + yv0 * Weff[cg] +
                    yv1 * Weff[NoutW + cg] + yv2 * Weff[2 * NoutW + cg] +
                    yv3 * Weff[3 * NoutW + cg];
        float ht = tanhf(pre);
        float z = (float)Zbf[(size_t)rg * 512 + cg];
        float hold = (float)Abf[(size_t)rg * 512 + cg];
        float hn = z * hold + (1.f - z) * ht;
        Obf[(size_t)rg * 512 + cg] = (__bf16)hn;
      }
    }
  } else {
#pragma unroll
    for (int r = 0; r < 4; r++) {
      int rg = row0 + w * 16 + quad * 4 + r;
      if (rg >= M) continue;
#pragma unroll
      for (int ni = 0; ni < NT; ni++) {
        int cg = col0 + ni * 16 + lm;
        Ofp[(size_t)rg * 256 + cg] = fmaxf(acc4[ni][r] + beff[cg], 0.f);
      }
    }
  }
}

// acc[i,c] = sum_t probs[t] * hist[t+1][i,c];  accRelu = bf16(relu(acc))
__global__ void k_acc(const __bf16* __restrict__ hist, const float* __restrict__ probs,
                      float* __restrict__ acc, __bf16* __restrict__ accRelu, int n) {
  int idx = blockIdx.x * blockDim.x + threadIdx.x;
  if (idx >= n * 64) return;
  size_t off = (size_t)idx * 8;
  size_t S = (size_t)n * 512;
  float s[8] = {0, 0, 0, 0, 0, 0, 0, 0};
#pragma unroll
  for (int t = 0; t < TT; t++) {
    float p = probs[t];
    v8bf h = *(const v8bf*)(hist + (size_t)(t + 1) * S + off);
#pragma unroll
    for (int j = 0; j < 8; j++) s[j] = fmaf(p, (float)h[j], s[j]);
  }
  *(float4*)(acc + off) = make_float4(s[0], s[1], s[2], s[3]);
  *(float4*)(acc + off + 4) = make_float4(s[4], s[5], s[6], s[7]);
  v8bf rl;
#pragma unroll
  for (int j = 0; j < 8; j++) rl[j] = (__bf16)fmaxf(s[j], 0.f);
  *(v8bf*)(accRelu + off) = rl;
}

__global__ void k_head2(const float* __restrict__ T1, const float* __restrict__ W2,
                        const float* __restrict__ b2, float* __restrict__ out0, int M) {
  int idx = blockIdx.x * blockDim.x + threadIdx.x;
  if (idx >= M * 12) return;
  int i = idx / 12, c = idx % 12;
  const float* tr = T1 + (size_t)i * 256;
  float s = b2[c];
  for (int k = 0; k < 256; k++) s = fmaf(tr[k], W2[k * 12 + c], s);
  out0[idx] = s;
}

// ---------------- launch ----------------

extern "C" void kernel_launch(void* const* d_in, const int* in_sizes, int n_in,
                              void* d_out, int out_size, void* d_ws, size_t ws_size,
                              hipStream_t stream) {
  const float* x   = (const float*)d_in[0];
  const int*   ei  = (const int*)d_in[1];
  const float* ea  = (const float*)d_in[2];
  const float* att = (const float*)d_in[3];
  const float* Wzg = (const float*)d_in[4];  const float* bzg = (const float*)d_in[5];
  const float* Wzl = (const float*)d_in[6];  const float* bzl = (const float*)d_in[7];
  const float* Wrg = (const float*)d_in[8];  const float* brg = (const float*)d_in[9];
  const float* Wrl = (const float*)d_in[10]; const float* brl = (const float*)d_in[11];
  const float* Whg = (const float*)d_in[12]; const float* bhg = (const float*)d_in[13];
  const float* Whl = (const float*)d_in[14]; const float* bhl = (const float*)d_in[15];
  const float* W1  = (const float*)d_in[16]; const float* b1  = (const float*)d_in[17];
  const float* W2  = (const float*)d_in[18]; const float* b2  = (const float*)d_in[19];

  const int N = in_sizes[0] / NF;
  const int E = in_sizes[1] / 2;
  const int* srcI = ei;
  const int* dstI = ei + E;

  float* out0 = (float*)d_out;                   // [N,12]
  float* accO = (float*)d_out + (size_t)N * 12;  // [N,512] = H_accum (output 1)

  char* wp = (char*)d_ws;
  auto carve = [&](size_t bytes) -> void* {
    void* p = (void*)wp;
    wp += (bytes + 255) & ~(size_t)255;
    return p;
  };
  float*  deg     = (float*)carve((size_t)N * 4);
  float*  dinv    = (float*)carve((size_t)N * 4);
  float*  probs   = (float*)carve(64);
  float*  Y       = (float*)carve((size_t)N * NF * 4);
  __bf16* WzrP    = (__bf16*)carve((size_t)1024 * 512 * 2);
  __bf16* WhP     = (__bf16*)carve((size_t)512 * 512 * 2);
  __bf16* W1P     = (__bf16*)carve((size_t)256 * 512 * 2);
  float*  Wzr_eff = (float*)carve((size_t)4 * 1024 * 4);
  float*  bzr_eff = (float*)carve((size_t)1024 * 4);
  float*  Wh_eff  = (float*)carve((size_t)4 * 512 * 4);
  float*  bh_eff  = (float*)carve((size_t)512 * 4);
  __bf16* hist    = (__bf16*)carve((size_t)(TT + 1) * N * 512 * 2);  // H_0..H_12 bf16
  __bf16* Zbf     = (__bf16*)carve((size_t)N * 512 * 2);
  __bf16* Rbf     = (__bf16*)carve((size_t)N * 512 * 2);
  __bf16* accRelu = (__bf16*)carve((size_t)N * 512 * 2);
  float*  T1      = (float*)carve((size_t)N * 256 * 4);
  int*    cnt     = (int*)carve((size_t)2 * N * 4);  // cnt[N] + fill[N] contiguous
  int*    fill    = cnt + N;
  int*    offs    = (int*)carve((size_t)(N + 1) * 4);
  int*    csrc    = (int*)carve((size_t)E * 4);
  float*  cw      = (float*)carve((size_t)E * 4);
  (void)ws_size; (void)n_in; (void)out_size;

  const int TPB = 256;
  auto cdiv = [](int a, int b) { return (a + b - 1) / b; };
  const size_t S = (size_t)N * 512;

  // degree + normalization
  k_init_deg<<<cdiv(N, TPB), TPB, 0, stream>>>(deg, N);
  k_scatter_deg<<<cdiv(E, TPB), TPB, 0, stream>>>(dstI, ea, deg, E);
  k_dinv<<<cdiv(N, TPB), TPB, 0, stream>>>(deg, dinv, N);

  // CSR by dst, then gather Y = Ahat @ X
  k_zeroi<<<cdiv(2 * N, TPB), TPB, 0, stream>>>(cnt, 2 * N);
  k_count<<<cdiv(E, TPB), TPB, 0, stream>>>(dstI, cnt, E);
  k_scan<<<1, 1024, 0, stream>>>(cnt, offs, N);
  k_place<<<cdiv(E, TPB), TPB, 0, stream>>>(srcI, dstI, ea, offs, fill, csrc, cw, E);
  k_gather<<<cdiv(N * 12, TPB), TPB, 0, stream>>>(offs, csrc, cw, dinv, x, Y, N);

  // weight prep (packed bf16 fragment tiles) + folded GCN weights
  k_t_zr<<<cdiv(1024 * 512, TPB), TPB, 0, stream>>>(Wzl, Wrl, WzrP);
  k_t_h<<<cdiv(512 * 512, TPB), TPB, 0, stream>>>(Whl, WhP);
  k_t_1<<<cdiv(256 * 512, TPB), TPB, 0, stream>>>(W1, W1P);
  k_build_eff<<<cdiv(5 * 512, TPB), TPB, 0, stream>>>(Wzg, Wzl, bzg, bzl, Wzr_eff, bzr_eff, 1024, 0);
  k_build_eff<<<cdiv(5 * 512, TPB), TPB, 0, stream>>>(Wrg, Wrl, brg, brl, Wzr_eff, bzr_eff, 1024, 512);
  k_build_eff<<<cdiv(5 * 512, TPB), TPB, 0, stream>>>(Whg, Whl, bhg, bhl, Wh_eff, bh_eff, 512, 0);
  k_softmax_att<<<1, 64, 0, stream>>>(att, probs);

  // hist slot 0 = H_0 = 0
  k_zeroi<<<cdiv(N * 256, TPB), TPB, 0, stream>>>((int*)hist, N * 256);

  const int gy = cdiv(N, 64);  // 157 row blocks
  for (int t = 0; t < TT; t++) {
    const __bf16* Hbt = hist + (size_t)t * S;
    __bf16* Hbn = hist + (size_t)(t + 1) * S;
    dim3 g0(4, gy);
    k_mm<0><<<g0, 256, 0, stream>>>(Hbt, WzrP, nullptr, nullptr, Y,
                                    Wzr_eff, bzr_eff, nullptr, Zbf, Rbf, N, t);
    dim3 g1(4, gy);
    k_mm<1><<<g1, 256, 0, stream>>>(Hbt, WhP, Rbf, Zbf, Y,
                                    Wh_eff, bh_eff, nullptr, Hbn, nullptr, N, t);
  }

  // H_accum = sum_t p_t H_{t+1}; head
  k_acc<<<cdiv(N * 64, TPB), TPB, 0, stream>>>(hist, probs, accO, accRelu, N);
  dim3 g2(1, gy);
  k_mm<2><<<g2, 256, 0, stream>>>(accRelu, W1P, nullptr, nullptr, nullptr,
                                  nullptr, b1, T1, nullptr, nullptr, N, 0);
  k_head2<<<cdiv(N * 12, TPB), TPB, 0, stream>>>(T1, W2, b2, out0, N);
}